// Round 1
// baseline (835.548 us; speedup 1.0000x reference)
//
#include <hip/hip_runtime.h>

typedef float f32x4 __attribute__((ext_vector_type(4)));

constexpr int   N     = 512;
constexpr int   NITER = 21;
constexpr float TINV  = 100.0f;   // 1 / temperature

// 1 block per matrix, 1024 threads = 16 waves.
// wave w owns rows [32w, 32w+32); lane l owns cols {4l..4l+3, 256+4l..259+4l}.
__launch_bounds__(1024)
__global__ void sinkhorn_kernel(const float* __restrict__ x,
                                float* __restrict__ out) {
    __shared__ alignas(16) float cpart[16][N];  // 32 KiB: per-wave column partials
    __shared__ float u_s[N];
    __shared__ alignas(16) float v_s[N];

    const int tid  = threadIdx.x;
    const int wave = tid >> 6;
    const int lane = tid & 63;
    const int j0   = lane << 2;        // low column quad; high quad at 256+j0

    const size_t base = (size_t)blockIdx.x * (size_t)(N * N);
    const float* __restrict__ xb = x + base;
    const int row0 = wave * 32;

    for (int j = tid; j < N; j += 1024) { u_s[j] = 0.0f; v_s[j] = 0.0f; }
    __syncthreads();

    for (int it = 0; it < NITER; ++it) {
        // this lane's v values (v^{it-1}) -> registers
        const f32x4 va = *(const f32x4*)&v_s[j0];
        const f32x4 vb = *(const f32x4*)&v_s[256 + j0];
        float vl[8] = {va.x, va.y, va.z, va.w, vb.x, vb.y, vb.z, vb.w};
        float cac[8] = {0.f, 0.f, 0.f, 0.f, 0.f, 0.f, 0.f, 0.f};

        #pragma unroll 4
        for (int r = 0; r < 32; ++r) {
            const int i = row0 + r;
            const float* row = xb + (size_t)i * N;
            const f32x4 xa = *(const f32x4*)(row + j0);
            const f32x4 xc = *(const f32x4*)(row + 256 + j0);
            float y[8] = {xa.x * TINV, xa.y * TINV, xa.z * TINV, xa.w * TINV,
                          xc.x * TINV, xc.y * TINV, xc.z * TINV, xc.w * TINV};
            float ush;
            if (it == 0) {
                // iteration 1: shift = row max (v == 0); exact LSE
                float m = y[0];
                #pragma unroll
                for (int k = 1; k < 8; ++k) m = fmaxf(m, y[k]);
                #pragma unroll
                for (int off = 32; off > 0; off >>= 1)
                    m = fmaxf(m, __shfl_xor(m, off, 64));
                ush = m;
            } else {
                // shift = u^{it-1}: y - v - u = log_alpha^{it-1} <= 0, exp-safe
                ush = u_s[i];
            }
            float e[8];
            float s = 0.0f;
            #pragma unroll
            for (int k = 0; k < 8; ++k) {
                e[k] = __expf(y[k] - vl[k] - ush);
                s += e[k];
            }
            #pragma unroll
            for (int off = 32; off > 0; off >>= 1)
                s += __shfl_xor(s, off, 64);
            s = fmaxf(s, 1e-37f);
            const float a = 1.0f / s;   // exp(ush - u_new)
            // column-side: exp(y - u_new - v^{it-1}) = E * a  (no exp needed)
            #pragma unroll
            for (int k = 0; k < 8; ++k) cac[k] = fmaf(e[k], a, cac[k]);
            if (lane == 0) u_s[i] = ush + __logf(s);   // u^{it}
        }

        // cross-wave column reduction -> v^{it}
        *(f32x4*)&cpart[wave][j0]       = (f32x4){cac[0], cac[1], cac[2], cac[3]};
        *(f32x4*)&cpart[wave][256 + j0] = (f32x4){cac[4], cac[5], cac[6], cac[7]};
        __syncthreads();
        if (tid < N) {
            float s = 0.0f;
            #pragma unroll
            for (int w = 0; w < 16; ++w) s += cpart[w][tid];
            s = fmaxf(s, 1e-37f);
            v_s[tid] += __logf(s);
        }
        __syncthreads();
    }

    // final: out = exp(y - u - v), nontemporal stores (don't evict x from L3)
    {
        const f32x4 va = *(const f32x4*)&v_s[j0];
        const f32x4 vb = *(const f32x4*)&v_s[256 + j0];
        const float vl[8] = {va.x, va.y, va.z, va.w, vb.x, vb.y, vb.z, vb.w};
        float* __restrict__ ob = out + base;
        #pragma unroll 2
        for (int r = 0; r < 32; ++r) {
            const int i = row0 + r;
            const float* row  = xb + (size_t)i * N;
            float*       orow = ob + (size_t)i * N;
            const f32x4 xa = *(const f32x4*)(row + j0);
            const f32x4 xc = *(const f32x4*)(row + 256 + j0);
            const float ush = u_s[i];
            f32x4 o0, o1;
            o0.x = __expf(xa.x * TINV - vl[0] - ush);
            o0.y = __expf(xa.y * TINV - vl[1] - ush);
            o0.z = __expf(xa.z * TINV - vl[2] - ush);
            o0.w = __expf(xa.w * TINV - vl[3] - ush);
            o1.x = __expf(xc.x * TINV - vl[4] - ush);
            o1.y = __expf(xc.y * TINV - vl[5] - ush);
            o1.z = __expf(xc.z * TINV - vl[6] - ush);
            o1.w = __expf(xc.w * TINV - vl[7] - ush);
            __builtin_nontemporal_store(o0, (f32x4*)(orow + j0));
            __builtin_nontemporal_store(o1, (f32x4*)(orow + 256 + j0));
        }
    }
}

extern "C" void kernel_launch(void* const* d_in, const int* in_sizes, int n_in,
                              void* d_out, int out_size, void* d_ws, size_t ws_size,
                              hipStream_t stream) {
    const float* x = (const float*)d_in[0];
    float* out = (float*)d_out;
    const int nmat = in_sizes[0] / (N * N);   // 256
    sinkhorn_kernel<<<nmat, 1024, 0, stream>>>(x, out);
}